// Round 1
// baseline (653.888 us; speedup 1.0000x reference)
//
#include <hip/hip_runtime.h>
#include <math.h>

// ---------------------------------------------------------------------------
// GCN 2-layer: h1 = relu(gcnconv(x,W1,b1)); out = log_softmax(gcnconv(h1,W2,b2))
// R7: (a) h2b padded to 64-elem rows (128B) so every agg2 per-edge gather is
//     exactly one aligned cache line (was 80B rows, ~1.75 lines/gather);
//     (b) gemm1 software-pipelined: register-prefetch chunk c+1 between the
//     barriers so global-load latency hides under MFMA (single LDS buffer,
//     occupancy unchanged).
// agg kernels: 8-edges x 8-lanes x 16B vectorized gathers, chunk-16 masked,
// shfl-xor cross-edge reduction per node. sEdge.y = dinv[row]; dinv[col]
// applied once per node (linearity). gemm2 fused into agg1 epilogue.
// N=100000, E=1600000, F: 512 -> 64 -> 40
// ---------------------------------------------------------------------------

#define FIN 512
#define FHID 64
#define FOUT 40
#define H2LD 64   // padded row stride (elements) for h2b: 128B lines

typedef __attribute__((ext_vector_type(8))) short short8;
typedef __attribute__((ext_vector_type(4))) float f32x4;
typedef unsigned short ushort_t;
typedef unsigned int uint_t;

__device__ __forceinline__ ushort_t bf16_rn(float f) {
    union { float f; uint_t u; } v; v.f = f;
    uint_t r = v.u + 0x7FFF + ((v.u >> 16) & 1);
    return (ushort_t)(r >> 16);
}
__device__ __forceinline__ uint_t pack_bf16(float a, float b) {
    return (uint_t)bf16_rn(a) | ((uint_t)bf16_rn(b) << 16);
}
__device__ __forceinline__ float bf16_to_f(ushort_t u) {
    union { uint_t i; float f; } t; t.i = ((uint_t)u) << 16; return t.f;
}
// accumulate 8 bf16 feats (one uint4) * nm into acc[8]
__device__ __forceinline__ void acc8(float* acc, uint4 g, float nm) {
    acc[0] = fmaf(__uint_as_float(g.x << 16), nm, acc[0]);
    acc[1] = fmaf(__uint_as_float(g.x & 0xFFFF0000u), nm, acc[1]);
    acc[2] = fmaf(__uint_as_float(g.y << 16), nm, acc[2]);
    acc[3] = fmaf(__uint_as_float(g.y & 0xFFFF0000u), nm, acc[3]);
    acc[4] = fmaf(__uint_as_float(g.z << 16), nm, acc[4]);
    acc[5] = fmaf(__uint_as_float(g.z & 0xFFFF0000u), nm, acc[5]);
    acc[6] = fmaf(__uint_as_float(g.w << 16), nm, acc[6]);
    acc[7] = fmaf(__uint_as_float(g.w & 0xFFFF0000u), nm, acc[7]);
}
__device__ __forceinline__ void unpack8(float* d, uint4 g) {
    d[0] = __uint_as_float(g.x << 16); d[1] = __uint_as_float(g.x & 0xFFFF0000u);
    d[2] = __uint_as_float(g.y << 16); d[3] = __uint_as_float(g.y & 0xFFFF0000u);
    d[4] = __uint_as_float(g.z << 16); d[5] = __uint_as_float(g.z & 0xFFFF0000u);
    d[6] = __uint_as_float(g.w << 16); d[7] = __uint_as_float(g.w & 0xFFFF0000u);
}

// ---------------- histogram of in-degree (x4 vectorized) ----------------
__global__ void hist_kernel(const int* __restrict__ col, int* __restrict__ deg, int E) {
    int i = (blockIdx.x * 256 + threadIdx.x) * 4;
    if (i + 3 < E) {
        int4 c = *reinterpret_cast<const int4*>(&col[i]);
        atomicAdd(&deg[c.x], 1); atomicAdd(&deg[c.y], 1);
        atomicAdd(&deg[c.z], 1); atomicAdd(&deg[c.w], 1);
    } else {
        for (int j = i; j < E; ++j) atomicAdd(&deg[col[j]], 1);
    }
}

__global__ void dinv_kernel(const int* __restrict__ deg, float* __restrict__ dinv, int n) {
    int i = blockIdx.x * 256 + threadIdx.x;
    if (i < n) dinv[i] = rsqrtf((float)deg[i] + 1.0f);
}

// ---------------- scan ----------------
__global__ void scan1_kernel(const int* __restrict__ deg, int* __restrict__ offs,
                             int* __restrict__ bsums, int n) {
    __shared__ int tmp[256];
    int tid = threadIdx.x;
    int i = blockIdx.x * 256 + tid;
    int v = (i < n) ? deg[i] : 0;
    tmp[tid] = v;
    __syncthreads();
    for (int off = 1; off < 256; off <<= 1) {
        int t = (tid >= off) ? tmp[tid - off] : 0;
        __syncthreads();
        tmp[tid] += t;
        __syncthreads();
    }
    if (i < n) offs[i] = tmp[tid] - v;
    if (tid == 255) bsums[blockIdx.x] = tmp[255];
}

__global__ void scan2_kernel(int* __restrict__ bsums, int nb) {
    __shared__ int tmp[512];
    int tid = threadIdx.x;
    int v = (tid < nb) ? bsums[tid] : 0;
    tmp[tid] = v;
    __syncthreads();
    for (int off = 1; off < 512; off <<= 1) {
        int t = (tid >= off) ? tmp[tid - off] : 0;
        __syncthreads();
        tmp[tid] += t;
        __syncthreads();
    }
    if (tid < nb) bsums[tid] = tmp[tid] - v;
}

__global__ void scan3_kernel(int* __restrict__ offs, const int* __restrict__ bsums,
                             int* __restrict__ cursor, int n) {
    int i = blockIdx.x * 256 + threadIdx.x;
    if (i < n) {
        int o = offs[i] + bsums[blockIdx.x];
        offs[i] = o;
        cursor[i] = o;
    }
}

// ---------------- build dest-sorted records {row, dinv[row]} ----------------
__global__ void build_kernel(const int* __restrict__ row, const int* __restrict__ col,
                             const float* __restrict__ dinv, int* __restrict__ cursor,
                             uint2* __restrict__ sEdge, int E) {
    int e = blockIdx.x * 256 + threadIdx.x;
    if (e < E) {
        int r = row[e], c = col[e];
        float nm = dinv[r];                       // dinv[c] applied per-node later
        int pos = atomicAdd(&cursor[c], 1);
        sEdge[pos] = make_uint2((uint_t)r, __float_as_uint(nm));
    }
}

// ---------------- W1 transpose + bf16 ----------------
__global__ void w1t_kernel(const float* __restrict__ W1, ushort_t* __restrict__ Wt) {
    int idx = blockIdx.x * 256 + threadIdx.x;   // 32768
    int nrow = idx >> 9;
    int k = idx & 511;
    Wt[idx] = bf16_rn(W1[k * 64 + nrow]);
}

// ---------------- GEMM1 (MFMA): h1b[N,64] = bf16( x[N,512] @ W1[512,64] ) ----
// R7: register-prefetch pipeline. Per chunk c: LDS-write(c); bar; issue
// global loads for c+1 (latency hides under MFMA); MFMA(c); bar.
#define LDA 72
#define LDB 72
__global__ __launch_bounds__(256) void gemm1_kernel(
    const float* __restrict__ x, const ushort_t* __restrict__ Wt,
    ushort_t* __restrict__ h1b, int n) {
    __shared__ ushort_t lA[128 * LDA];
    __shared__ ushort_t lB[64 * LDB];

    int tid = threadIdx.x;
    int wave = tid >> 6, lane = tid & 63;
    int quad = lane >> 4, m16 = lane & 15;
    int node0 = blockIdx.x * 128;

    // staging coords: constant per thread across chunks
    int r0 = tid >> 4, k4 = tid & 15;    // A: rows r0+16i, 16B at col k4*4
    int nr0 = tid >> 3, seg = tid & 7;   // B: rows nr0+32i, 16B at col seg*8

    f32x4 zero = {0.f, 0.f, 0.f, 0.f};
    f32x4 acc[2][4];
#pragma unroll
    for (int mt = 0; mt < 2; ++mt)
#pragma unroll
        for (int nt = 0; nt < 4; ++nt) acc[mt][nt] = zero;

    float4 ra[8];
    uint4 rb[2];

    // prologue: load chunk 0 into registers
#pragma unroll
    for (int i = 0; i < 8; ++i) {
        int node = node0 + r0 + i * 16;
        float4 v = make_float4(0.f, 0.f, 0.f, 0.f);
        if (node < n) v = *reinterpret_cast<const float4*>(&x[(size_t)node * FIN + k4 * 4]);
        ra[i] = v;
    }
#pragma unroll
    for (int i = 0; i < 2; ++i)
        rb[i] = *reinterpret_cast<const uint4*>(&Wt[(size_t)(nr0 + i * 32) * FIN + seg * 8]);

    for (int c = 0; c < 8; ++c) {
        // write staged registers to LDS (pack A to bf16 here)
#pragma unroll
        for (int i = 0; i < 8; ++i)
            *reinterpret_cast<uint2*>(&lA[(r0 + i * 16) * LDA + k4 * 4]) =
                make_uint2(pack_bf16(ra[i].x, ra[i].y), pack_bf16(ra[i].z, ra[i].w));
#pragma unroll
        for (int i = 0; i < 2; ++i)
            *reinterpret_cast<uint4*>(&lB[(nr0 + i * 32) * LDB + seg * 8]) = rb[i];
        __syncthreads();

        // issue next chunk's global loads; vmcnt-wait lands after MFMA+barrier
        if (c < 7) {
            int kc = (c + 1) * 64;
#pragma unroll
            for (int i = 0; i < 8; ++i) {
                int node = node0 + r0 + i * 16;
                float4 v = make_float4(0.f, 0.f, 0.f, 0.f);
                if (node < n)
                    v = *reinterpret_cast<const float4*>(&x[(size_t)node * FIN + kc + k4 * 4]);
                ra[i] = v;
            }
#pragma unroll
            for (int i = 0; i < 2; ++i)
                rb[i] = *reinterpret_cast<const uint4*>(
                    &Wt[(size_t)(nr0 + i * 32) * FIN + kc + seg * 8]);
        }

#pragma unroll
        for (int kk = 0; kk < 2; ++kk) {
            short8 a[2], b[4];
#pragma unroll
            for (int mt = 0; mt < 2; ++mt)
                a[mt] = *reinterpret_cast<const short8*>(
                    &lA[(wave * 32 + mt * 16 + m16) * LDA + kk * 32 + quad * 8]);
#pragma unroll
            for (int nt = 0; nt < 4; ++nt)
                b[nt] = *reinterpret_cast<const short8*>(
                    &lB[(nt * 16 + m16) * LDB + kk * 32 + quad * 8]);
#pragma unroll
            for (int mt = 0; mt < 2; ++mt)
#pragma unroll
                for (int nt = 0; nt < 4; ++nt)
                    acc[mt][nt] = __builtin_amdgcn_mfma_f32_16x16x32_bf16(
                        a[mt], b[nt], acc[mt][nt], 0, 0, 0);
        }
        __syncthreads();
    }

#pragma unroll
    for (int mt = 0; mt < 2; ++mt) {
#pragma unroll
        for (int reg = 0; reg < 4; ++reg) {
            int node = node0 + wave * 32 + mt * 16 + quad * 4 + reg;
            if (node < n) {
#pragma unroll
                for (int nt = 0; nt < 4; ++nt)
                    h1b[(size_t)node * 64 + nt * 16 + m16] = bf16_rn(acc[mt][nt][reg]);
            }
        }
    }
}

// ---------------- fused agg1 + self-loop + bias + relu + GEMM2 ----------------
// wave = node; layout: 8 edges x 8 lanes x 16B gathers; cross-edge shfl-xor
// reduce; epilogue redistributes via LDS then shfl matvec into W2.
__global__ __launch_bounds__(256) void agg1f_kernel(
    const int* __restrict__ offs, const int* __restrict__ deg,
    const uint2* __restrict__ sEdge, const ushort_t* __restrict__ h1b,
    const float* __restrict__ dinv, const float* __restrict__ b1,
    const float* __restrict__ W2, ushort_t* __restrict__ h2b, int n) {
    __shared__ float lw2[64 * FOUT];
    __shared__ float lb1[64];
    __shared__ float lh[4][64];
    int tid = threadIdx.x;
#pragma unroll
    for (int r = 0; r < 10; ++r) lw2[tid + r * 256] = W2[tid + r * 256];
    if (tid < 64) lb1[tid] = b1[tid];

    int wv = tid >> 6, lane = tid & 63;
    int e8 = lane >> 3, c = lane & 7;
    int node = blockIdx.x * 4 + wv;
    bool valid = node < n;
    int start = valid ? offs[node] : 0;
    int cnt = valid ? deg[node] : 0;

    float acc[8];
#pragma unroll
    for (int j = 0; j < 8; ++j) acc[j] = 0.f;

    for (int base = 0; base < cnt; base += 16) {
        int i0 = base + e8, i1 = i0 + 8;
        uint2 e0 = (i0 < cnt) ? sEdge[start + i0] : make_uint2(0u, 0u);
        uint2 e1 = (i1 < cnt) ? sEdge[start + i1] : make_uint2(0u, 0u);
        uint4 g0 = *reinterpret_cast<const uint4*>(&h1b[(size_t)e0.x * 64 + c * 8]);
        uint4 g1 = *reinterpret_cast<const uint4*>(&h1b[(size_t)e1.x * 64 + c * 8]);
        acc8(acc, g0, __uint_as_float(e0.y));
        acc8(acc, g1, __uint_as_float(e1.y));
    }
#pragma unroll
    for (int mask = 8; mask <= 32; mask <<= 1)
#pragma unroll
        for (int j = 0; j < 8; ++j) acc[j] += __shfl_xor(acc[j], mask);

    if (valid && e8 == 0) {
        *reinterpret_cast<float4*>(&lh[wv][c * 8]) =
            make_float4(acc[0], acc[1], acc[2], acc[3]);
        *reinterpret_cast<float4*>(&lh[wv][c * 8 + 4]) =
            make_float4(acc[4], acc[5], acc[6], acc[7]);
    }
    __syncthreads();

    float v = 0.f;
    if (valid) {
        float di = dinv[node];
        float self = bf16_to_f(h1b[(size_t)node * 64 + lane]) * di;
        v = fmaxf(fmaf(lh[wv][lane] + self, di, lb1[lane]), 0.f);
    }

    // h2[j] = sum_k v[k] * W2[k][j], j = lane (0..39 active)
    float o0 = 0.f, o1 = 0.f;
#pragma unroll
    for (int kk = 0; kk < 64; kk += 4) {
        float a0 = __shfl(v, kk), a1 = __shfl(v, kk + 1);
        float a2 = __shfl(v, kk + 2), a3 = __shfl(v, kk + 3);
        o0 = fmaf(a0, lw2[kk * FOUT + lane], o0);
        o1 = fmaf(a1, lw2[(kk + 1) * FOUT + lane], o1);
        o0 = fmaf(a2, lw2[(kk + 2) * FOUT + lane], o0);
        o1 = fmaf(a3, lw2[(kk + 3) * FOUT + lane], o1);
    }
    if (valid && lane < FOUT)
        h2b[(size_t)node * H2LD + lane] = bf16_rn(o0 + o1);
}

// ---------------- fused agg2 + self-loop + bias + log_softmax ----------------
// wave = node; 8 edges x (5 of 8) lanes x 16B gathers over 128B-padded rows:
// each per-edge gather is exactly one aligned cache line.
__global__ __launch_bounds__(256) void agg2_kernel(
    const int* __restrict__ offs, const int* __restrict__ deg,
    const uint2* __restrict__ sEdge, const ushort_t* __restrict__ h2b,
    const float* __restrict__ dinv, const float* __restrict__ b2,
    float* __restrict__ out, int n) {
    __shared__ float lb2[40];
    int tid = threadIdx.x;
    if (tid < 40) lb2[tid] = b2[tid];
    __syncthreads();

    int wv = tid >> 6, lane = tid & 63;
    int e8 = lane >> 3, c = lane & 7;
    bool act = c < 5;
    int co = (act ? c : 4) * 8;           // clamped chunk offset (feats)
    int node = blockIdx.x * 4 + wv;
    if (node >= n) return;                // wave-uniform; barrier already passed
    int start = offs[node];
    int cnt = deg[node];

    float acc[8];
#pragma unroll
    for (int j = 0; j < 8; ++j) acc[j] = 0.f;

    for (int base = 0; base < cnt; base += 16) {
        int i0 = base + e8, i1 = i0 + 8;
        uint2 e0 = (i0 < cnt) ? sEdge[start + i0] : make_uint2(0u, 0u);
        uint2 e1 = (i1 < cnt) ? sEdge[start + i1] : make_uint2(0u, 0u);
        uint4 g0 = *reinterpret_cast<const uint4*>(&h2b[(size_t)e0.x * H2LD + co]);
        uint4 g1 = *reinterpret_cast<const uint4*>(&h2b[(size_t)e1.x * H2LD + co]);
        acc8(acc, g0, __uint_as_float(e0.y));
        acc8(acc, g1, __uint_as_float(e1.y));
    }
#pragma unroll
    for (int mask = 8; mask <= 32; mask <<= 1)
#pragma unroll
        for (int j = 0; j < 8; ++j) acc[j] += __shfl_xor(acc[j], mask);

    float di = dinv[node];
    uint4 sg = *reinterpret_cast<const uint4*>(&h2b[(size_t)node * H2LD + co]);
    float self[8];
    unpack8(self, sg);
    float raw[8];
#pragma unroll
    for (int j = 0; j < 8; ++j)
        raw[j] = fmaf(acc[j] + self[j] * di, di, lb2[co + j]);

    float pm = -INFINITY;
    if (act) {
#pragma unroll
        for (int j = 0; j < 8; ++j) pm = fmaxf(pm, raw[j]);
    }
#pragma unroll
    for (int mask = 1; mask <= 4; mask <<= 1) pm = fmaxf(pm, __shfl_xor(pm, mask));
    float s = 0.f;
    if (act) {
#pragma unroll
        for (int j = 0; j < 8; ++j) s += expf(raw[j] - pm);
    }
#pragma unroll
    for (int mask = 1; mask <= 4; mask <<= 1) s += __shfl_xor(s, mask);
    float ls = logf(s) + pm;

    if (act && e8 == 0) {
        float* op = &out[(size_t)node * FOUT + co];
        *reinterpret_cast<float4*>(op) =
            make_float4(raw[0] - ls, raw[1] - ls, raw[2] - ls, raw[3] - ls);
        *reinterpret_cast<float4*>(op + 4) =
            make_float4(raw[4] - ls, raw[5] - ls, raw[6] - ls, raw[7] - ls);
    }
}

// ---------------------------------------------------------------------------
extern "C" void kernel_launch(void* const* d_in, const int* in_sizes, int n_in,
                              void* d_out, int out_size, void* d_ws, size_t ws_size,
                              hipStream_t stream) {
    const float* x  = (const float*)d_in[0];
    const int*   ei = (const int*)d_in[1];
    const float* W1 = (const float*)d_in[2];
    const float* b1 = (const float*)d_in[3];
    const float* W2 = (const float*)d_in[4];
    const float* b2 = (const float*)d_in[5];
    float* out = (float*)d_out;

    int n = in_sizes[0] / FIN;        // 100000
    int E = in_sizes[1] / 2;          // 1600000
    const int* row = ei;
    const int* col = ei + E;

    // workspace layout (4-byte words), ~40 MB total
    int* wsi = (int*)d_ws;
    const size_t NR = 100352;
    int*      deg    = wsi;                                  // [NR]
    float*    dinv   = (float*)(wsi + NR);                   // [NR]
    int*      offs   = wsi + 2 * NR;                         // [NR]
    int*      cursor = wsi + 3 * NR;                         // [NR]
    int*      bsums  = wsi + 4 * NR;                         // [512]
    ushort_t* Wt     = (ushort_t*)(wsi + 4 * NR + 512);      // [64*512] bf16
    uint2*    sEdge  = (uint2*)(wsi + 4 * NR + 512 + 16384); // [E] {row, dinv[row]}
    ushort_t* h1b    = (ushort_t*)(sEdge + (size_t)E);       // [n*64] bf16
    ushort_t* h2b    = h1b + (size_t)n * 64;                 // [n*H2LD] bf16 (padded)

    int nb = (n + 255) / 256;   // 391

    // ---- CSR build ----
    hipMemsetAsync(deg, 0, (size_t)n * 4, stream);
    hist_kernel<<<(E / 4 + 255) / 256, 256, 0, stream>>>(col, deg, E);
    dinv_kernel<<<nb, 256, 0, stream>>>(deg, dinv, n);
    scan1_kernel<<<nb, 256, 0, stream>>>(deg, offs, bsums, n);
    scan2_kernel<<<1, 512, 0, stream>>>(bsums, nb);
    scan3_kernel<<<nb, 256, 0, stream>>>(offs, bsums, cursor, n);
    build_kernel<<<(E + 255) / 256, 256, 0, stream>>>(row, col, dinv, cursor, sEdge, E);

    // ---- layer 1 (+ fused layer-2 transform) ----
    w1t_kernel<<<128, 256, 0, stream>>>(W1, Wt);
    gemm1_kernel<<<(n + 127) / 128, 256, 0, stream>>>(x, Wt, h1b, n);
    agg1f_kernel<<<(n + 3) / 4, 256, 0, stream>>>(offs, deg, sEdge, h1b, dinv, b1, W2, h2b, n);

    // ---- layer 2 aggregation + log_softmax ----
    agg2_kernel<<<(n + 3) / 4, 256, 0, stream>>>(offs, deg, sEdge, h2b, dinv, b2, out, n);
}

// Round 3
// 581.894 us; speedup vs baseline: 1.1237x; 1.1237x over previous
//
#include <hip/hip_runtime.h>
#include <math.h>

// ---------------------------------------------------------------------------
// GCN 2-layer: h1 = relu(gcnconv(x,W1,b1)); out = log_softmax(gcnconv(h1,W2,b2))
// R9 (= R8 + workspace-overlap fix): layer-2 linear map moved OUT of the
// per-node epilogue using linearity:
//   out = log_softmax( agg2(relu(agg1(x@W1)+b1)) @ W2 + b2 )
// - agg kernels are pure gather+reduce (DS ops/node 154 -> ~27: the 64
//   ds_bpermute + 64 ds_read_b32 shfl-matvec is gone)
// - gemm2sm: [N,64]@[64,40] MFMA kernel (W2 split hi/lo bf16 for f32-accuracy)
//   with fused bias + log_softmax in the C-fragment layout
// - gather loop chunk-32: 4 gathers in flight (Poisson(16) degrees -> 99% of
//   nodes complete in one latency chain)
// - FIX vs R8: sEdge was overlapping w2lo (offset missed w2lo's 1536 words);
//   sEdge now derived from w2lo end.
// N=100000, E=1600000, F: 512 -> 64 -> 40
// ---------------------------------------------------------------------------

#define FIN 512
#define FHID 64
#define FOUT 40

typedef __attribute__((ext_vector_type(8))) short short8;
typedef __attribute__((ext_vector_type(4))) float f32x4;
typedef unsigned short ushort_t;
typedef unsigned int uint_t;

__device__ __forceinline__ ushort_t bf16_rn(float f) {
    union { float f; uint_t u; } v; v.f = f;
    uint_t r = v.u + 0x7FFF + ((v.u >> 16) & 1);
    return (ushort_t)(r >> 16);
}
__device__ __forceinline__ uint_t pack_bf16(float a, float b) {
    return (uint_t)bf16_rn(a) | ((uint_t)bf16_rn(b) << 16);
}
__device__ __forceinline__ float bf16_to_f(ushort_t u) {
    union { uint_t i; float f; } t; t.i = ((uint_t)u) << 16; return t.f;
}
// accumulate 8 bf16 feats (one uint4) * nm into acc[8]
__device__ __forceinline__ void acc8(float* acc, uint4 g, float nm) {
    acc[0] = fmaf(__uint_as_float(g.x << 16), nm, acc[0]);
    acc[1] = fmaf(__uint_as_float(g.x & 0xFFFF0000u), nm, acc[1]);
    acc[2] = fmaf(__uint_as_float(g.y << 16), nm, acc[2]);
    acc[3] = fmaf(__uint_as_float(g.y & 0xFFFF0000u), nm, acc[3]);
    acc[4] = fmaf(__uint_as_float(g.z << 16), nm, acc[4]);
    acc[5] = fmaf(__uint_as_float(g.z & 0xFFFF0000u), nm, acc[5]);
    acc[6] = fmaf(__uint_as_float(g.w << 16), nm, acc[6]);
    acc[7] = fmaf(__uint_as_float(g.w & 0xFFFF0000u), nm, acc[7]);
}

// ---------------- histogram of in-degree (x4 vectorized) ----------------
__global__ void hist_kernel(const int* __restrict__ col, int* __restrict__ deg, int E) {
    int i = (blockIdx.x * 256 + threadIdx.x) * 4;
    if (i + 3 < E) {
        int4 c = *reinterpret_cast<const int4*>(&col[i]);
        atomicAdd(&deg[c.x], 1); atomicAdd(&deg[c.y], 1);
        atomicAdd(&deg[c.z], 1); atomicAdd(&deg[c.w], 1);
    } else {
        for (int j = i; j < E; ++j) atomicAdd(&deg[col[j]], 1);
    }
}

__global__ void dinv_kernel(const int* __restrict__ deg, float* __restrict__ dinv, int n) {
    int i = blockIdx.x * 256 + threadIdx.x;
    if (i < n) dinv[i] = rsqrtf((float)deg[i] + 1.0f);
}

// ---------------- scan ----------------
__global__ void scan1_kernel(const int* __restrict__ deg, int* __restrict__ offs,
                             int* __restrict__ bsums, int n) {
    __shared__ int tmp[256];
    int tid = threadIdx.x;
    int i = blockIdx.x * 256 + tid;
    int v = (i < n) ? deg[i] : 0;
    tmp[tid] = v;
    __syncthreads();
    for (int off = 1; off < 256; off <<= 1) {
        int t = (tid >= off) ? tmp[tid - off] : 0;
        __syncthreads();
        tmp[tid] += t;
        __syncthreads();
    }
    if (i < n) offs[i] = tmp[tid] - v;
    if (tid == 255) bsums[blockIdx.x] = tmp[255];
}

__global__ void scan2_kernel(int* __restrict__ bsums, int nb) {
    __shared__ int tmp[512];
    int tid = threadIdx.x;
    int v = (tid < nb) ? bsums[tid] : 0;
    tmp[tid] = v;
    __syncthreads();
    for (int off = 1; off < 512; off <<= 1) {
        int t = (tid >= off) ? tmp[tid - off] : 0;
        __syncthreads();
        tmp[tid] += t;
        __syncthreads();
    }
    if (tid < nb) bsums[tid] = tmp[tid] - v;
}

__global__ void scan3_kernel(int* __restrict__ offs, const int* __restrict__ bsums,
                             int* __restrict__ cursor, int n) {
    int i = blockIdx.x * 256 + threadIdx.x;
    if (i < n) {
        int o = offs[i] + bsums[blockIdx.x];
        offs[i] = o;
        cursor[i] = o;
    }
}

// ---------------- build dest-sorted records {row, dinv[row]} ----------------
__global__ void build_kernel(const int* __restrict__ row, const int* __restrict__ col,
                             const float* __restrict__ dinv, int* __restrict__ cursor,
                             uint2* __restrict__ sEdge, int E) {
    int e = blockIdx.x * 256 + threadIdx.x;
    if (e < E) {
        int r = row[e], c = col[e];
        float nm = dinv[r];                       // dinv[c] applied per-node later
        int pos = atomicAdd(&cursor[c], 1);
        sEdge[pos] = make_uint2((uint_t)r, __float_as_uint(nm));
    }
}

// ---------------- W1 transpose + bf16 ----------------
__global__ void w1t_kernel(const float* __restrict__ W1, ushort_t* __restrict__ Wt) {
    int idx = blockIdx.x * 256 + threadIdx.x;   // 32768
    int nrow = idx >> 9;
    int k = idx & 511;
    Wt[idx] = bf16_rn(W1[k * 64 + nrow]);
}

// ---------------- W2 transpose + hi/lo bf16 split ----------------
// w2hi/w2lo: [48][64] bf16, rows 40..47 zero. hi+lo recovers ~f32 W2.
__global__ void w2split_kernel(const float* __restrict__ W2,
                               ushort_t* __restrict__ w2hi, ushort_t* __restrict__ w2lo) {
    int idx = blockIdx.x * 256 + threadIdx.x;   // 48*64 = 3072
    if (idx >= 3072) return;
    int j = idx >> 6, k = idx & 63;
    float w = (j < FOUT) ? W2[k * FOUT + j] : 0.f;
    ushort_t h = bf16_rn(w);
    float rest = w - bf16_to_f(h);
    w2hi[idx] = h;
    w2lo[idx] = bf16_rn(rest);
}

// ---------------- GEMM1 (MFMA): h1b[N,64] = bf16( x[N,512] @ W1[512,64] ) ----
// register-prefetch pipeline (single LDS buffer).
#define LDA 72
#define LDB 72
__global__ __launch_bounds__(256) void gemm1_kernel(
    const float* __restrict__ x, const ushort_t* __restrict__ Wt,
    ushort_t* __restrict__ h1b, int n) {
    __shared__ ushort_t lA[128 * LDA];
    __shared__ ushort_t lB[64 * LDB];

    int tid = threadIdx.x;
    int wave = tid >> 6, lane = tid & 63;
    int quad = lane >> 4, m16 = lane & 15;
    int node0 = blockIdx.x * 128;

    int r0 = tid >> 4, k4 = tid & 15;    // A: rows r0+16i, 16B at col k4*4
    int nr0 = tid >> 3, seg = tid & 7;   // B: rows nr0+32i, 16B at col seg*8

    f32x4 zero = {0.f, 0.f, 0.f, 0.f};
    f32x4 acc[2][4];
#pragma unroll
    for (int mt = 0; mt < 2; ++mt)
#pragma unroll
        for (int nt = 0; nt < 4; ++nt) acc[mt][nt] = zero;

    float4 ra[8];
    uint4 rb[2];

#pragma unroll
    for (int i = 0; i < 8; ++i) {
        int node = node0 + r0 + i * 16;
        float4 v = make_float4(0.f, 0.f, 0.f, 0.f);
        if (node < n) v = *reinterpret_cast<const float4*>(&x[(size_t)node * FIN + k4 * 4]);
        ra[i] = v;
    }
#pragma unroll
    for (int i = 0; i < 2; ++i)
        rb[i] = *reinterpret_cast<const uint4*>(&Wt[(size_t)(nr0 + i * 32) * FIN + seg * 8]);

    for (int c = 0; c < 8; ++c) {
#pragma unroll
        for (int i = 0; i < 8; ++i)
            *reinterpret_cast<uint2*>(&lA[(r0 + i * 16) * LDA + k4 * 4]) =
                make_uint2(pack_bf16(ra[i].x, ra[i].y), pack_bf16(ra[i].z, ra[i].w));
#pragma unroll
        for (int i = 0; i < 2; ++i)
            *reinterpret_cast<uint4*>(&lB[(nr0 + i * 32) * LDB + seg * 8]) = rb[i];
        __syncthreads();

        if (c < 7) {
            int kc = (c + 1) * 64;
#pragma unroll
            for (int i = 0; i < 8; ++i) {
                int node = node0 + r0 + i * 16;
                float4 v = make_float4(0.f, 0.f, 0.f, 0.f);
                if (node < n)
                    v = *reinterpret_cast<const float4*>(&x[(size_t)node * FIN + kc + k4 * 4]);
                ra[i] = v;
            }
#pragma unroll
            for (int i = 0; i < 2; ++i)
                rb[i] = *reinterpret_cast<const uint4*>(
                    &Wt[(size_t)(nr0 + i * 32) * FIN + kc + seg * 8]);
        }

#pragma unroll
        for (int kk = 0; kk < 2; ++kk) {
            short8 a[2], b[4];
#pragma unroll
            for (int mt = 0; mt < 2; ++mt)
                a[mt] = *reinterpret_cast<const short8*>(
                    &lA[(wave * 32 + mt * 16 + m16) * LDA + kk * 32 + quad * 8]);
#pragma unroll
            for (int nt = 0; nt < 4; ++nt)
                b[nt] = *reinterpret_cast<const short8*>(
                    &lB[(nt * 16 + m16) * LDB + kk * 32 + quad * 8]);
#pragma unroll
            for (int mt = 0; mt < 2; ++mt)
#pragma unroll
                for (int nt = 0; nt < 4; ++nt)
                    acc[mt][nt] = __builtin_amdgcn_mfma_f32_16x16x32_bf16(
                        a[mt], b[nt], acc[mt][nt], 0, 0, 0);
        }
        __syncthreads();
    }

#pragma unroll
    for (int mt = 0; mt < 2; ++mt) {
#pragma unroll
        for (int reg = 0; reg < 4; ++reg) {
            int node = node0 + wave * 32 + mt * 16 + quad * 4 + reg;
            if (node < n) {
#pragma unroll
                for (int nt = 0; nt < 4; ++nt)
                    h1b[(size_t)node * 64 + nt * 16 + m16] = bf16_rn(acc[mt][nt][reg]);
            }
        }
    }
}

// ---------------- pure aggregation kernel (templated) ----------------
// wave = node; 8 edges x 8 lanes x 16B gathers, chunk-32 (4 in flight),
// shfl-xor cross-edge reduce, lh redistribute, self + norm.
// MODE 0: dst = bf16(relu(agg + b1))   (src = h1b)
// MODE 1: dst = bf16(agg)              (src = h1a)
template <int MODE>
__global__ __launch_bounds__(256) void agg_kernel(
    const int* __restrict__ offs, const int* __restrict__ deg,
    const uint2* __restrict__ sEdge, const ushort_t* __restrict__ src,
    const float* __restrict__ dinv, const float* __restrict__ b1,
    ushort_t* __restrict__ dst, int n) {
    __shared__ float lb1[64];
    __shared__ float lh[4][64];
    int tid = threadIdx.x;
    if (MODE == 0 && tid < 64) lb1[tid] = b1[tid];

    int wv = tid >> 6, lane = tid & 63;
    int e8 = lane >> 3, c = lane & 7;
    int node = blockIdx.x * 4 + wv;
    bool valid = node < n;
    int start = valid ? offs[node] : 0;
    int cnt = valid ? deg[node] : 0;

    float acc[8];
#pragma unroll
    for (int j = 0; j < 8; ++j) acc[j] = 0.f;

    uint2 z2 = make_uint2(0u, 0u);
    for (int base = 0; base < cnt; base += 32) {
        int i0 = base + e8, i1 = i0 + 8, i2 = i0 + 16, i3 = i0 + 24;
        uint2 e0 = (i0 < cnt) ? sEdge[start + i0] : z2;
        uint2 e1 = (i1 < cnt) ? sEdge[start + i1] : z2;
        uint2 e2 = (i2 < cnt) ? sEdge[start + i2] : z2;
        uint2 e3 = (i3 < cnt) ? sEdge[start + i3] : z2;
        uint4 g0 = *reinterpret_cast<const uint4*>(&src[(size_t)e0.x * 64 + c * 8]);
        uint4 g1 = *reinterpret_cast<const uint4*>(&src[(size_t)e1.x * 64 + c * 8]);
        uint4 g2 = *reinterpret_cast<const uint4*>(&src[(size_t)e2.x * 64 + c * 8]);
        uint4 g3 = *reinterpret_cast<const uint4*>(&src[(size_t)e3.x * 64 + c * 8]);
        acc8(acc, g0, __uint_as_float(e0.y));
        acc8(acc, g1, __uint_as_float(e1.y));
        acc8(acc, g2, __uint_as_float(e2.y));
        acc8(acc, g3, __uint_as_float(e3.y));
    }
#pragma unroll
    for (int mask = 8; mask <= 32; mask <<= 1)
#pragma unroll
        for (int j = 0; j < 8; ++j) acc[j] += __shfl_xor(acc[j], mask);

    if (valid && e8 == 0) {
        *reinterpret_cast<float4*>(&lh[wv][c * 8]) =
            make_float4(acc[0], acc[1], acc[2], acc[3]);
        *reinterpret_cast<float4*>(&lh[wv][c * 8 + 4]) =
            make_float4(acc[4], acc[5], acc[6], acc[7]);
    }
    __syncthreads();

    if (valid) {
        float di = dinv[node];
        float self = bf16_to_f(src[(size_t)node * 64 + lane]) * di;
        float v = (lh[wv][lane] + self) * di;
        if (MODE == 0) v = fmaxf(v + lb1[lane], 0.f);
        dst[(size_t)node * 64 + lane] = bf16_rn(v);
    }
}

// ---------------- GEMM2 + bias + log_softmax (MFMA) ----------------
// out[N,40] = log_softmax( A[N,64] @ W2[64,40] + b2 ), W2 as hi+lo bf16.
// Tile: 128 nodes x 48 cols, K=64 (single stage). C-layout epilogue softmax.
#define LDC 72
__global__ __launch_bounds__(256) void gemm2sm_kernel(
    const ushort_t* __restrict__ A, const ushort_t* __restrict__ w2hi,
    const ushort_t* __restrict__ w2lo, const float* __restrict__ b2,
    float* __restrict__ out, int n) {
    __shared__ ushort_t lA[128 * LDC];
    __shared__ ushort_t lBh[48 * LDC];
    __shared__ ushort_t lBl[48 * LDC];

    int tid = threadIdx.x;
    int wave = tid >> 6, lane = tid & 63;
    int quad = lane >> 4, m16 = lane & 15;
    int node0 = blockIdx.x * 128;

    // stage A tile: 128 rows x 64 bf16; 2 threads/row, 64B each
    {
        int r = tid & 127, part = tid >> 7;
        int node = node0 + r;
        uint4 z = make_uint4(0u, 0u, 0u, 0u);
        const uint4* sp = reinterpret_cast<const uint4*>(&A[(size_t)node * 64 + part * 32]);
#pragma unroll
        for (int i = 0; i < 4; ++i) {
            uint4 v = (node < n) ? sp[i] : z;
            *reinterpret_cast<uint4*>(&lA[r * LDC + part * 32 + i * 8]) = v;
        }
    }
    // stage B tiles: 48*64 bf16 = 384 uint4 each
    for (int i = tid; i < 384; i += 256) {
        int row = i >> 3, seg = i & 7;
        *reinterpret_cast<uint4*>(&lBh[row * LDC + seg * 8]) =
            reinterpret_cast<const uint4*>(w2hi)[i];
        *reinterpret_cast<uint4*>(&lBl[row * LDC + seg * 8]) =
            reinterpret_cast<const uint4*>(w2lo)[i];
    }
    // per-lane bias (j = nt*16 + m16)
    float rb2_0 = b2[m16];
    float rb2_1 = b2[16 + m16];
    float rb2_2 = (m16 < 8) ? b2[32 + m16] : 0.f;
    __syncthreads();

    f32x4 zero = {0.f, 0.f, 0.f, 0.f};
    f32x4 acc[2][3];
#pragma unroll
    for (int mt = 0; mt < 2; ++mt)
#pragma unroll
        for (int nt = 0; nt < 3; ++nt) acc[mt][nt] = zero;

#pragma unroll
    for (int kk = 0; kk < 2; ++kk) {
        short8 a[2], bh[3], bl[3];
#pragma unroll
        for (int mt = 0; mt < 2; ++mt)
            a[mt] = *reinterpret_cast<const short8*>(
                &lA[(wave * 32 + mt * 16 + m16) * LDC + kk * 32 + quad * 8]);
#pragma unroll
        for (int nt = 0; nt < 3; ++nt) {
            bh[nt] = *reinterpret_cast<const short8*>(
                &lBh[(nt * 16 + m16) * LDC + kk * 32 + quad * 8]);
            bl[nt] = *reinterpret_cast<const short8*>(
                &lBl[(nt * 16 + m16) * LDC + kk * 32 + quad * 8]);
        }
#pragma unroll
        for (int mt = 0; mt < 2; ++mt)
#pragma unroll
            for (int nt = 0; nt < 3; ++nt) {
                acc[mt][nt] = __builtin_amdgcn_mfma_f32_16x16x32_bf16(
                    a[mt], bh[nt], acc[mt][nt], 0, 0, 0);
                acc[mt][nt] = __builtin_amdgcn_mfma_f32_16x16x32_bf16(
                    a[mt], bl[nt], acc[mt][nt], 0, 0, 0);
            }
    }

    // epilogue: bias + log_softmax per node-row (cols spread over 16 lanes x 3 nt)
    bool c2 = (m16 < 8);   // nt=2 col j=32+m16 valid iff m16<8
#pragma unroll
    for (int mt = 0; mt < 2; ++mt) {
#pragma unroll
        for (int reg = 0; reg < 4; ++reg) {
            int node = node0 + wave * 32 + mt * 16 + quad * 4 + reg;
            float r0 = acc[mt][0][reg] + rb2_0;
            float r1 = acc[mt][1][reg] + rb2_1;
            float r2 = acc[mt][2][reg] + rb2_2;
            float pm = fmaxf(fmaxf(r0, r1), c2 ? r2 : -INFINITY);
#pragma unroll
            for (int mask = 1; mask <= 8; mask <<= 1)
                pm = fmaxf(pm, __shfl_xor(pm, mask));
            float s = expf(r0 - pm) + expf(r1 - pm) + (c2 ? expf(r2 - pm) : 0.f);
#pragma unroll
            for (int mask = 1; mask <= 8; mask <<= 1)
                s += __shfl_xor(s, mask);
            float ls = logf(s) + pm;
            if (node < n) {
                float* op = &out[(size_t)node * FOUT];
                op[m16] = r0 - ls;
                op[16 + m16] = r1 - ls;
                if (c2) op[32 + m16] = r2 - ls;
            }
        }
    }
}

// ---------------------------------------------------------------------------
extern "C" void kernel_launch(void* const* d_in, const int* in_sizes, int n_in,
                              void* d_out, int out_size, void* d_ws, size_t ws_size,
                              hipStream_t stream) {
    const float* x  = (const float*)d_in[0];
    const int*   ei = (const int*)d_in[1];
    const float* W1 = (const float*)d_in[2];
    const float* b1 = (const float*)d_in[3];
    const float* W2 = (const float*)d_in[4];
    const float* b2 = (const float*)d_in[5];
    float* out = (float*)d_out;

    int n = in_sizes[0] / FIN;        // 100000
    int E = in_sizes[1] / 2;          // 1600000
    const int* row = ei;
    const int* col = ei + E;

    // workspace layout (4-byte words), ~40 MB total
    int* wsi = (int*)d_ws;
    const size_t NR = 100352;
    int*      deg    = wsi;                                  // [NR]
    float*    dinv   = (float*)(wsi + NR);                   // [NR]
    int*      offs   = wsi + 2 * NR;                         // [NR]
    int*      cursor = wsi + 3 * NR;                         // [NR]
    int*      bsums  = wsi + 4 * NR;                         // [512]
    ushort_t* Wt     = (ushort_t*)(wsi + 4 * NR + 512);      // [64*512] bf16
    ushort_t* w2hi   = Wt + 64 * 512;                        // [48*64] bf16
    ushort_t* w2lo   = w2hi + 48 * 64;                       // [48*64] bf16
    uint2*    sEdge  = (uint2*)(w2lo + 48 * 64);             // [E] (after w2lo!)
    ushort_t* h1b    = (ushort_t*)(sEdge + (size_t)E);       // [n*64] bf16 (then A)
    ushort_t* h1a    = h1b + (size_t)n * 64;                 // [n*64] bf16
    ushort_t* Abuf   = h1b;                                  // reuse: h1b dead after agg<0>

    int nb = (n + 255) / 256;   // 391

    // ---- CSR build ----
    hipMemsetAsync(deg, 0, (size_t)n * 4, stream);
    hist_kernel<<<(E / 4 + 255) / 256, 256, 0, stream>>>(col, deg, E);
    dinv_kernel<<<nb, 256, 0, stream>>>(deg, dinv, n);
    scan1_kernel<<<nb, 256, 0, stream>>>(deg, offs, bsums, n);
    scan2_kernel<<<1, 512, 0, stream>>>(bsums, nb);
    scan3_kernel<<<nb, 256, 0, stream>>>(offs, bsums, cursor, n);
    build_kernel<<<(E + 255) / 256, 256, 0, stream>>>(row, col, dinv, cursor, sEdge, E);

    // ---- weights prep ----
    w1t_kernel<<<128, 256, 0, stream>>>(W1, Wt);
    w2split_kernel<<<12, 256, 0, stream>>>(W2, w2hi, w2lo);

    // ---- layer 1 transform ----
    gemm1_kernel<<<(n + 127) / 128, 256, 0, stream>>>(x, Wt, h1b, n);

    // ---- aggregation 1 (+bias+relu) -> h1a ----
    agg_kernel<0><<<(n + 3) / 4, 256, 0, stream>>>(offs, deg, sEdge, h1b, dinv, b1, h1a, n);

    // ---- aggregation 2 (pure) -> Abuf ----
    agg_kernel<1><<<(n + 3) / 4, 256, 0, stream>>>(offs, deg, sEdge, h1a, dinv, b1, Abuf, n);

    // ---- layer 2 transform + bias + log_softmax ----
    gemm2sm_kernel<<<(n + 127) / 128, 256, 0, stream>>>(Abuf, w2hi, w2lo, b2, out, n);
}